// Round 3
// baseline (294.463 us; speedup 1.0000x reference)
//
#include <hip/hip_runtime.h>

static constexpr float HS3 = 0.35355339059327373f; // (1/sqrt(2))^3

// s[m], m = sz*4 + sy*2 + sx (subband bits); o[p], p = pz*4 + py*2 + px
__device__ __forceinline__ void ihaar8(const float s[8], float o[8]) {
    float ex[8];
#pragma unroll
    for (int m = 0; m < 8; m += 2) { ex[m] = s[m] + s[m + 1]; ex[m + 1] = s[m] - s[m + 1]; }
    float ey[8];
#pragma unroll
    for (int i = 0; i < 2; ++i)
#pragma unroll
        for (int px = 0; px < 2; ++px) {
            ey[i * 4 + 0 + px] = ex[i * 4 + 0 + px] + ex[i * 4 + 2 + px];
            ey[i * 4 + 2 + px] = ex[i * 4 + 0 + px] - ex[i * 4 + 2 + px];
        }
#pragma unroll
    for (int q = 0; q < 4; ++q) {
        o[q]     = (ey[q] + ey[4 + q]) * HS3;
        o[4 + q] = (ey[q] - ey[4 + q]) * HS3;
    }
}

__device__ __forceinline__ unsigned short f2bf(float f) {
    unsigned int u = __float_as_uint(f);
    unsigned int r = (u + 0x7FFFu + ((u >> 16) & 1u)) >> 16; // RNE
    return (unsigned short)r;
}

// Levels 0/1, LDS-staged: A [8][R^3] f32, det [7][8][R^3] f32 -> out [8][(2R)^3] f32 (c-major).
// 512 threads/block, tile = 256 consecutive cells; phase-1 wave loads pull 1 KiB
// contiguous per stream; phase-2 LDS reads at [s*256+cell] are conflict-free.
template <int R>
__global__ __launch_bounds__(512) void idwt_passB(const float* __restrict__ A,
                                                  const float* __restrict__ det,
                                                  float* __restrict__ out) {
    const int R3 = R * R * R;
    __shared__ float4 lds4[64][64]; // [stream][float4-chunk] = 64 KiB

    int T0 = blockIdx.x * 256;
    int t = threadIdx.x;
    int wave = t >> 6, lane = t & 63;

#pragma unroll
    for (int k = 0; k < 8; ++k) {
        int s = wave * 8 + k; // s<8: A channel s; else det (s-8) = b*8+c
        const float* base = (s < 8) ? (A + (size_t)s * R3) : (det + (size_t)(s - 8) * R3);
        lds4[s][lane] = reinterpret_cast<const float4*>(base)[(T0 >> 2) + lane];
    }
    __syncthreads();

    int cell = t & 255;
    int h = t >> 8; // channels h*4 .. h*4+3
    int cid = T0 + cell;
    int X = cid & (R - 1);
    int Y = (cid / R) & (R - 1);
    int Z = cid / (R * R);

    const float* ld = reinterpret_cast<const float*>(&lds4[0][0]); // [s*256 + cell]
    const int Ro = 2 * R;
    float2* out2 = reinterpret_cast<float2*>(out);

#pragma unroll
    for (int cc = 0; cc < 4; ++cc) {
        int c = h * 4 + cc;
        float s8[8];
        s8[0] = ld[c * 256 + cell];
#pragma unroll
        for (int b = 0; b < 7; ++b) s8[b + 1] = ld[(8 + b * 8 + c) * 256 + cell];
        float o[8];
        ihaar8(s8, o);
#pragma unroll
        for (int pz = 0; pz < 2; ++pz)
#pragma unroll
            for (int py = 0; py < 2; ++py) {
                size_t idx = ((size_t)(c * Ro + 2 * Z + pz) * Ro + (2 * Y + py)) * R + X;
                out2[idx] = make_float2(o[pz * 4 + py * 2 + 0], o[pz * 4 + py * 2 + 1]);
            }
    }
}

// Level 2: vol2 [8][128^3] f32 + detail2 [7][8][128^3] f32 -> vol3 channel-last bf16 [256][256][256][8]
__global__ __launch_bounds__(512) void idwt_passC2(const float* __restrict__ A,
                                                   const float* __restrict__ det,
                                                   unsigned short* __restrict__ out) {
    const int R3 = 128 * 128 * 128;
    __shared__ float4 lds4[64][64];

    int T0 = blockIdx.x * 256;
    int t = threadIdx.x;
    int wave = t >> 6, lane = t & 63;

#pragma unroll
    for (int k = 0; k < 8; ++k) {
        int s = wave * 8 + k;
        const float* base = (s < 8) ? (A + (size_t)s * R3) : (det + (size_t)(s - 8) * R3);
        lds4[s][lane] = reinterpret_cast<const float4*>(base)[(T0 >> 2) + lane];
    }
    __syncthreads();

    int cell = t & 255;
    int h = t >> 8;
    int cid = T0 + cell;
    int Z = cid >> 14;
    int r2 = cid & 16383;
    int Y = r2 >> 7;
    int X = r2 & 127;

    const float* ld = reinterpret_cast<const float*>(&lds4[0][0]);

    float ob[8][4]; // [parity][cc]
#pragma unroll
    for (int cc = 0; cc < 4; ++cc) {
        int c = h * 4 + cc;
        float s8[8];
        s8[0] = ld[c * 256 + cell];
#pragma unroll
        for (int b = 0; b < 7; ++b) s8[b + 1] = ld[(8 + b * 8 + c) * 256 + cell];
        float o[8];
        ihaar8(s8, o);
#pragma unroll
        for (int p = 0; p < 8; ++p) ob[p][cc] = o[p];
    }

    uint2* out2 = reinterpret_cast<uint2*>(out);
#pragma unroll
    for (int pz = 0; pz < 2; ++pz)
#pragma unroll
        for (int py = 0; py < 2; ++py)
#pragma unroll
            for (int px = 0; px < 2; ++px) {
                int p = pz * 4 + py * 2 + px;
                size_t vox = (((size_t)(2 * Z + pz) * 256 + (2 * Y + py)) * 256 + (2 * X + px));
                uint2 v;
                v.x = (unsigned int)f2bf(ob[p][0]) | ((unsigned int)f2bf(ob[p][1]) << 16);
                v.y = (unsigned int)f2bf(ob[p][2]) | ((unsigned int)f2bf(ob[p][3]) << 16);
                out2[vox * 2 + h] = v;
            }
}

__device__ __forceinline__ float map_grid(float v) {
    float g = (v * (1.0f / 1.5f) + 1.0f) * (0.5f * 255.0f);
    return fminf(fmaxf(g, 0.0f), 255.0f);
}

__global__ void sample_kernel(const float* __restrict__ xyz, const unsigned short* __restrict__ vol,
                              float* __restrict__ out, int N) {
    int i = blockIdx.x * blockDim.x + threadIdx.x;
    if (i >= N) return;
    float gx = map_grid(xyz[3 * i + 0]);
    float gy = map_grid(xyz[3 * i + 1]);
    float gz = map_grid(xyz[3 * i + 2]);
    float x0f = floorf(gx), y0f = floorf(gy), z0f = floorf(gz);
    int x0 = (int)x0f, y0 = (int)y0f, z0 = (int)z0f;
    float fx = gx - x0f, fy = gy - y0f, fz = gz - z0f;
    int x1 = min(x0 + 1, 255), y1 = min(y0 + 1, 255), z1 = min(z0 + 1, 255);
    float wx0 = 1.0f - fx, wy0 = 1.0f - fy, wz0 = 1.0f - fz;

    float acc[8];
#pragma unroll
    for (int k = 0; k < 8; ++k) acc[k] = 0.0f;

    auto corner = [&](int z, int y, int x, float w) {
        const uint4* v4 = reinterpret_cast<const uint4*>(vol + ((((size_t)z * 256 + y) * 256 + x) << 3));
        uint4 a = *v4; // 8 bf16
        acc[0] += w * __uint_as_float(a.x << 16);
        acc[1] += w * __uint_as_float(a.x & 0xFFFF0000u);
        acc[2] += w * __uint_as_float(a.y << 16);
        acc[3] += w * __uint_as_float(a.y & 0xFFFF0000u);
        acc[4] += w * __uint_as_float(a.z << 16);
        acc[5] += w * __uint_as_float(a.z & 0xFFFF0000u);
        acc[6] += w * __uint_as_float(a.w << 16);
        acc[7] += w * __uint_as_float(a.w & 0xFFFF0000u);
    };
    corner(z0, y0, x0, wz0 * wy0 * wx0);
    corner(z0, y0, x1, wz0 * wy0 * fx);
    corner(z0, y1, x0, wz0 * fy * wx0);
    corner(z0, y1, x1, wz0 * fy * fx);
    corner(z1, y0, x0, fz * wy0 * wx0);
    corner(z1, y0, x1, fz * wy0 * fx);
    corner(z1, y1, x0, fz * fy * wx0);
    corner(z1, y1, x1, fz * fy * fx);

    float4* o4 = reinterpret_cast<float4*>(out + (size_t)i * 8);
    o4[0] = make_float4(acc[0], acc[1], acc[2], acc[3]);
    o4[1] = make_float4(acc[4], acc[5], acc[6], acc[7]);
}

extern "C" void kernel_launch(void* const* d_in, const int* in_sizes, int n_in,
                              void* d_out, int out_size, void* d_ws, size_t ws_size,
                              hipStream_t stream) {
    const float* xyz     = (const float*)d_in[0];
    const float* approx  = (const float*)d_in[1];
    const float* detail0 = (const float*)d_in[2];
    const float* detail1 = (const float*)d_in[3];
    const float* detail2 = (const float*)d_in[4];
    float* out = (float*)d_out;
    int N = in_sizes[0] / 3;

    char* ws = (char*)d_ws;
    float* vol1 = (float*)ws;                                    // 8*64^3  f32 =   8 MiB
    float* vol2 = (float*)(ws + (size_t)8 * 1024 * 1024);        // 8*128^3 f32 =  64 MiB
    unsigned short* vol3 = (unsigned short*)(ws + (size_t)72 * 1024 * 1024); // 256^3*8 bf16 = 256 MiB

    // Level 0: 32 -> 64 (LDS-staged)
    idwt_passB<32><<<(32 * 32 * 32) / 256, 512, 0, stream>>>(approx, detail0, vol1);
    // Level 1: 64 -> 128 (LDS-staged)
    idwt_passB<64><<<(64 * 64 * 64) / 256, 512, 0, stream>>>(vol1, detail1, vol2);
    // Level 2: 128 -> 256, channel-last bf16
    idwt_passC2<<<(128 * 128 * 128) / 256, 512, 0, stream>>>(vol2, detail2, vol3);
    // Trilinear sampling from bf16 channel-last volume
    sample_kernel<<<(N + 255) / 256, 256, 0, stream>>>(xyz, vol3, out, N);
}

// Round 4
// 285.780 us; speedup vs baseline: 1.0304x; 1.0304x over previous
//
#include <hip/hip_runtime.h>

static constexpr float HS3 = 0.35355339059327373f; // (1/sqrt(2))^3

// s[m], m = sz*4 + sy*2 + sx (subband bits); o[p], p = pz*4 + py*2 + px
__device__ __forceinline__ void ihaar8(const float s[8], float o[8]) {
    float ex[8];
#pragma unroll
    for (int m = 0; m < 8; m += 2) { ex[m] = s[m] + s[m + 1]; ex[m + 1] = s[m] - s[m + 1]; }
    float ey[8];
#pragma unroll
    for (int i = 0; i < 2; ++i)
#pragma unroll
        for (int px = 0; px < 2; ++px) {
            ey[i * 4 + 0 + px] = ex[i * 4 + 0 + px] + ex[i * 4 + 2 + px];
            ey[i * 4 + 2 + px] = ex[i * 4 + 0 + px] - ex[i * 4 + 2 + px];
        }
#pragma unroll
    for (int q = 0; q < 4; ++q) {
        o[q]     = (ey[q] + ey[4 + q]) * HS3;
        o[4 + q] = (ey[q] - ey[4 + q]) * HS3;
    }
}

__device__ __forceinline__ unsigned short f2bf(float f) {
    unsigned int u = __float_as_uint(f);
    unsigned int r = (u + 0x7FFFu + ((u >> 16) & 1u)) >> 16; // RNE
    return (unsigned short)r;
}

// Levels 0/1, LDS-staged: A [8][R^3] f32, det [7][8][R^3] f32 -> out [8][(2R)^3] f32 (c-major).
template <int R>
__global__ __launch_bounds__(512) void idwt_passB(const float* __restrict__ A,
                                                  const float* __restrict__ det,
                                                  float* __restrict__ out) {
    const int R3 = R * R * R;
    __shared__ float4 lds4[64][64]; // [stream][float4-chunk] = 64 KiB

    int T0 = blockIdx.x * 256;
    int t = threadIdx.x;
    int wave = t >> 6, lane = t & 63;

#pragma unroll
    for (int k = 0; k < 8; ++k) {
        int s = wave * 8 + k; // s<8: A channel s; else det (s-8) = b*8+c
        const float* base = (s < 8) ? (A + (size_t)s * R3) : (det + (size_t)(s - 8) * R3);
        lds4[s][lane] = reinterpret_cast<const float4*>(base)[(T0 >> 2) + lane];
    }
    __syncthreads();

    int cell = t & 255;
    int h = t >> 8; // channels h*4 .. h*4+3
    int cid = T0 + cell;
    int X = cid & (R - 1);
    int Y = (cid / R) & (R - 1);
    int Z = cid / (R * R);

    const float* ld = reinterpret_cast<const float*>(&lds4[0][0]); // [s*256 + cell]
    const int Ro = 2 * R;
    float2* out2 = reinterpret_cast<float2*>(out);

#pragma unroll
    for (int cc = 0; cc < 4; ++cc) {
        int c = h * 4 + cc;
        float s8[8];
        s8[0] = ld[c * 256 + cell];
#pragma unroll
        for (int b = 0; b < 7; ++b) s8[b + 1] = ld[(8 + b * 8 + c) * 256 + cell];
        float o[8];
        ihaar8(s8, o);
#pragma unroll
        for (int pz = 0; pz < 2; ++pz)
#pragma unroll
            for (int py = 0; py < 2; ++py) {
                size_t idx = ((size_t)(c * Ro + 2 * Z + pz) * Ro + (2 * Y + py)) * R + X;
                out2[idx] = make_float2(o[pz * 4 + py * 2 + 0], o[pz * 4 + py * 2 + 1]);
            }
    }
}

// Level 2: vol2 [8][128^3] f32 + detail2 [7][8][128^3] f32 -> vol3 channel-last bf16 [256][256][256][8].
// Phase 2 mapping cell=t>>1, h=t&1: lane l stores at byte base+l*8 -> fully contiguous
// 512B wave stores; LDS reads are 2-way bank-aliased (free per m136).
__global__ __launch_bounds__(512) void idwt_passC2(const float* __restrict__ A,
                                                   const float* __restrict__ det,
                                                   unsigned short* __restrict__ out) {
    const int R3 = 128 * 128 * 128;
    __shared__ float4 lds4[64][64];

    int T0 = blockIdx.x * 256;
    int t = threadIdx.x;
    int wave = t >> 6, lane = t & 63;

#pragma unroll
    for (int k = 0; k < 8; ++k) {
        int s = wave * 8 + k;
        const float* base = (s < 8) ? (A + (size_t)s * R3) : (det + (size_t)(s - 8) * R3);
        lds4[s][lane] = reinterpret_cast<const float4*>(base)[(T0 >> 2) + lane];
    }
    __syncthreads();

    int cell = t >> 1;   // 256 cells
    int h = t & 1;       // channel half: h*4 .. h*4+3
    int cid = T0 + cell;
    int Z = cid >> 14;
    int r2 = cid & 16383;
    int Y = r2 >> 7;
    int X = r2 & 127;

    const float* ld = reinterpret_cast<const float*>(&lds4[0][0]);

    float ob[8][4]; // [parity][cc]
#pragma unroll
    for (int cc = 0; cc < 4; ++cc) {
        int c = h * 4 + cc;
        float s8[8];
        s8[0] = ld[c * 256 + cell];
#pragma unroll
        for (int b = 0; b < 7; ++b) s8[b + 1] = ld[(8 + b * 8 + c) * 256 + cell];
        float o[8];
        ihaar8(s8, o);
#pragma unroll
        for (int p = 0; p < 8; ++p) ob[p][cc] = o[p];
    }

    uint2* out2 = reinterpret_cast<uint2*>(out);
#pragma unroll
    for (int pz = 0; pz < 2; ++pz)
#pragma unroll
        for (int py = 0; py < 2; ++py)
#pragma unroll
            for (int px = 0; px < 2; ++px) {
                int p = pz * 4 + py * 2 + px;
                size_t vox = (((size_t)(2 * Z + pz) * 256 + (2 * Y + py)) * 256 + (2 * X + px));
                uint2 v;
                v.x = (unsigned int)f2bf(ob[p][0]) | ((unsigned int)f2bf(ob[p][1]) << 16);
                v.y = (unsigned int)f2bf(ob[p][2]) | ((unsigned int)f2bf(ob[p][3]) << 16);
                out2[vox * 2 + h] = v;
            }
}

__device__ __forceinline__ float map_grid(float v) {
    float g = (v * (1.0f / 1.5f) + 1.0f) * (0.5f * 255.0f);
    return fminf(fmaxf(g, 0.0f), 255.0f);
}

__global__ void sample_kernel(const float* __restrict__ xyz, const unsigned short* __restrict__ vol,
                              float* __restrict__ out, int N) {
    int i = blockIdx.x * blockDim.x + threadIdx.x;
    if (i >= N) return;
    float gx = map_grid(xyz[3 * i + 0]);
    float gy = map_grid(xyz[3 * i + 1]);
    float gz = map_grid(xyz[3 * i + 2]);
    float x0f = floorf(gx), y0f = floorf(gy), z0f = floorf(gz);
    int x0 = (int)x0f, y0 = (int)y0f, z0 = (int)z0f;
    float fx = gx - x0f, fy = gy - y0f, fz = gz - z0f;
    int x1 = min(x0 + 1, 255), y1 = min(y0 + 1, 255), z1 = min(z0 + 1, 255);
    float wx0 = 1.0f - fx, wy0 = 1.0f - fy, wz0 = 1.0f - fz;

    float acc[8];
#pragma unroll
    for (int k = 0; k < 8; ++k) acc[k] = 0.0f;

    auto corner = [&](int z, int y, int x, float w) {
        const uint4* v4 = reinterpret_cast<const uint4*>(vol + ((((size_t)z * 256 + y) * 256 + x) << 3));
        uint4 a = *v4; // 8 bf16
        acc[0] += w * __uint_as_float(a.x << 16);
        acc[1] += w * __uint_as_float(a.x & 0xFFFF0000u);
        acc[2] += w * __uint_as_float(a.y << 16);
        acc[3] += w * __uint_as_float(a.y & 0xFFFF0000u);
        acc[4] += w * __uint_as_float(a.z << 16);
        acc[5] += w * __uint_as_float(a.z & 0xFFFF0000u);
        acc[6] += w * __uint_as_float(a.w << 16);
        acc[7] += w * __uint_as_float(a.w & 0xFFFF0000u);
    };
    corner(z0, y0, x0, wz0 * wy0 * wx0);
    corner(z0, y0, x1, wz0 * wy0 * fx);
    corner(z0, y1, x0, wz0 * fy * wx0);
    corner(z0, y1, x1, wz0 * fy * fx);
    corner(z1, y0, x0, fz * wy0 * wx0);
    corner(z1, y0, x1, fz * wy0 * fx);
    corner(z1, y1, x0, fz * fy * wx0);
    corner(z1, y1, x1, fz * fy * fx);

    float4* o4 = reinterpret_cast<float4*>(out + (size_t)i * 8);
    o4[0] = make_float4(acc[0], acc[1], acc[2], acc[3]);
    o4[1] = make_float4(acc[4], acc[5], acc[6], acc[7]);
}

extern "C" void kernel_launch(void* const* d_in, const int* in_sizes, int n_in,
                              void* d_out, int out_size, void* d_ws, size_t ws_size,
                              hipStream_t stream) {
    const float* xyz     = (const float*)d_in[0];
    const float* approx  = (const float*)d_in[1];
    const float* detail0 = (const float*)d_in[2];
    const float* detail1 = (const float*)d_in[3];
    const float* detail2 = (const float*)d_in[4];
    float* out = (float*)d_out;
    int N = in_sizes[0] / 3;

    char* ws = (char*)d_ws;
    float* vol1 = (float*)ws;                                    // 8*64^3  f32 =   8 MiB
    float* vol2 = (float*)(ws + (size_t)8 * 1024 * 1024);        // 8*128^3 f32 =  64 MiB
    unsigned short* vol3 = (unsigned short*)(ws + (size_t)72 * 1024 * 1024); // 256^3*8 bf16 = 256 MiB

    // Level 0: 32 -> 64 (LDS-staged)
    idwt_passB<32><<<(32 * 32 * 32) / 256, 512, 0, stream>>>(approx, detail0, vol1);
    // Level 1: 64 -> 128 (LDS-staged)
    idwt_passB<64><<<(64 * 64 * 64) / 256, 512, 0, stream>>>(vol1, detail1, vol2);
    // Level 2: 128 -> 256, channel-last bf16, contiguous wave stores
    idwt_passC2<<<(128 * 128 * 128) / 256, 512, 0, stream>>>(vol2, detail2, vol3);
    // Trilinear sampling from bf16 channel-last volume
    sample_kernel<<<(N + 255) / 256, 256, 0, stream>>>(xyz, vol3, out, N);
}

// Round 6
// 281.337 us; speedup vs baseline: 1.0467x; 1.0158x over previous
//
#include <hip/hip_runtime.h>

static constexpr float HS3 = 0.35355339059327373f; // (1/sqrt(2))^3

__device__ __forceinline__ void ihaar8(const float s[8], float o[8]) {
    float ex[8];
#pragma unroll
    for (int m = 0; m < 8; m += 2) { ex[m] = s[m] + s[m + 1]; ex[m + 1] = s[m] - s[m + 1]; }
    float ey[8];
#pragma unroll
    for (int i = 0; i < 2; ++i)
#pragma unroll
        for (int px = 0; px < 2; ++px) {
            ey[i * 4 + 0 + px] = ex[i * 4 + 0 + px] + ex[i * 4 + 2 + px];
            ey[i * 4 + 2 + px] = ex[i * 4 + 0 + px] - ex[i * 4 + 2 + px];
        }
#pragma unroll
    for (int q = 0; q < 4; ++q) {
        o[q]     = (ey[q] + ey[4 + q]) * HS3;
        o[4 + q] = (ey[q] - ey[4 + q]) * HS3;
    }
}

__device__ __forceinline__ unsigned short f2bf(float f) {
    unsigned int u = __float_as_uint(f);
    unsigned int r = (u + 0x7FFFu + ((u >> 16) & 1u)) >> 16; // RNE
    return (unsigned short)r;
}

// Levels 0/1, LDS-staged: A [8][R^3] f32, det [7][8][R^3] f32 -> out [8][(2R)^3] f32 (c-major).
template <int R>
__global__ __launch_bounds__(512) void idwt_passB(const float* __restrict__ A,
                                                  const float* __restrict__ det,
                                                  float* __restrict__ out) {
    const int R3 = R * R * R;
    __shared__ float4 lds4[64][64]; // [stream][float4-chunk] = 64 KiB

    int T0 = blockIdx.x * 256;
    int t = threadIdx.x;
    int wave = t >> 6, lane = t & 63;

#pragma unroll
    for (int k = 0; k < 8; ++k) {
        int s = wave * 8 + k; // s<8: A channel s; else det (s-8) = b*8+c
        const float* base = (s < 8) ? (A + (size_t)s * R3) : (det + (size_t)(s - 8) * R3);
        lds4[s][lane] = reinterpret_cast<const float4*>(base)[(T0 >> 2) + lane];
    }
    __syncthreads();

    int cell = t & 255;
    int h = t >> 8; // channels h*4 .. h*4+3
    int cid = T0 + cell;
    int X = cid & (R - 1);
    int Y = (cid / R) & (R - 1);
    int Z = cid / (R * R);

    const float* ld = reinterpret_cast<const float*>(&lds4[0][0]); // [s*256 + cell]
    const int Ro = 2 * R;
    float2* out2 = reinterpret_cast<float2*>(out);

#pragma unroll
    for (int cc = 0; cc < 4; ++cc) {
        int c = h * 4 + cc;
        float s8[8];
        s8[0] = ld[c * 256 + cell];
#pragma unroll
        for (int b = 0; b < 7; ++b) s8[b + 1] = ld[(8 + b * 8 + c) * 256 + cell];
        float o[8];
        ihaar8(s8, o);
#pragma unroll
        for (int pz = 0; pz < 2; ++pz)
#pragma unroll
            for (int py = 0; py < 2; ++py) {
                size_t idx = ((size_t)(c * Ro + 2 * Z + pz) * Ro + (2 * Y + py)) * R + X;
                out2[idx] = make_float2(o[pz * 4 + py * 2 + 0], o[pz * 4 + py * 2 + 1]);
            }
    }
}

// Level 2 with XCD-aware tile swizzle (8192 % 8 == 0 -> bijective): each XCD reads
// sequential 1 KiB chunks of all 64 source streams instead of 8 KiB-strided ones.
__global__ __launch_bounds__(512) void idwt_passC2(const float* __restrict__ A,
                                                   const float* __restrict__ det,
                                                   unsigned short* __restrict__ out) {
    const int R3 = 128 * 128 * 128;
    __shared__ float4 lds4[64][64];

    int b = blockIdx.x;
    int tile = (b & 7) * 1024 + (b >> 3); // XCD-contiguous tile assignment
    int T0 = tile * 256;
    int t = threadIdx.x;
    int wave = t >> 6, lane = t & 63;

#pragma unroll
    for (int k = 0; k < 8; ++k) {
        int s = wave * 8 + k;
        const float* base = (s < 8) ? (A + (size_t)s * R3) : (det + (size_t)(s - 8) * R3);
        lds4[s][lane] = reinterpret_cast<const float4*>(base)[(T0 >> 2) + lane];
    }
    __syncthreads();

    int cell = t >> 1;   // 256 cells
    int h = t & 1;       // channel half: h*4 .. h*4+3 -> lane l stores at byte base+l*8 (contiguous)
    int cid = T0 + cell;
    int Z = cid >> 14;
    int r2 = cid & 16383;
    int Y = r2 >> 7;
    int X = r2 & 127;

    const float* ld = reinterpret_cast<const float*>(&lds4[0][0]);

    float ob[8][4]; // [parity][cc]
#pragma unroll
    for (int cc = 0; cc < 4; ++cc) {
        int c = h * 4 + cc;
        float s8[8];
        s8[0] = ld[c * 256 + cell];
#pragma unroll
        for (int b7 = 0; b7 < 7; ++b7) s8[b7 + 1] = ld[(8 + b7 * 8 + c) * 256 + cell];
        float o[8];
        ihaar8(s8, o);
#pragma unroll
        for (int p = 0; p < 8; ++p) ob[p][cc] = o[p];
    }

    uint2* out2 = reinterpret_cast<uint2*>(out);
#pragma unroll
    for (int pz = 0; pz < 2; ++pz)
#pragma unroll
        for (int py = 0; py < 2; ++py)
#pragma unroll
            for (int px = 0; px < 2; ++px) {
                int p = pz * 4 + py * 2 + px;
                size_t vox = (((size_t)(2 * Z + pz) * 256 + (2 * Y + py)) * 256 + (2 * X + px));
                uint2 v;
                v.x = (unsigned int)f2bf(ob[p][0]) | ((unsigned int)f2bf(ob[p][1]) << 16);
                v.y = (unsigned int)f2bf(ob[p][2]) | ((unsigned int)f2bf(ob[p][3]) << 16);
                out2[vox * 2 + h] = v;
            }
}

__device__ __forceinline__ float map_grid(float v) {
    float g = (v * (1.0f / 1.5f) + 1.0f) * (0.5f * 255.0f);
    return fminf(fmaxf(g, 0.0f), 255.0f);
}

__global__ void sample_kernel(const float* __restrict__ xyz, const unsigned short* __restrict__ vol,
                              float* __restrict__ out, int N) {
    int i = blockIdx.x * blockDim.x + threadIdx.x;
    if (i >= N) return;
    float gx = map_grid(xyz[3 * i + 0]);
    float gy = map_grid(xyz[3 * i + 1]);
    float gz = map_grid(xyz[3 * i + 2]);
    float x0f = floorf(gx), y0f = floorf(gy), z0f = floorf(gz);
    int x0 = (int)x0f, y0 = (int)y0f, z0 = (int)z0f;
    float fx = gx - x0f, fy = gy - y0f, fz = gz - z0f;
    int x1 = min(x0 + 1, 255), y1 = min(y0 + 1, 255), z1 = min(z0 + 1, 255);
    float wx0 = 1.0f - fx, wy0 = 1.0f - fy, wz0 = 1.0f - fz;

    float acc[8];
#pragma unroll
    for (int k = 0; k < 8; ++k) acc[k] = 0.0f;

    auto corner = [&](int z, int y, int x, float w) {
        const uint4* v4 = reinterpret_cast<const uint4*>(vol + ((((size_t)z * 256 + y) * 256 + x) << 3));
        uint4 a = *v4; // 8 bf16
        acc[0] += w * __uint_as_float(a.x << 16);
        acc[1] += w * __uint_as_float(a.x & 0xFFFF0000u);
        acc[2] += w * __uint_as_float(a.y << 16);
        acc[3] += w * __uint_as_float(a.y & 0xFFFF0000u);
        acc[4] += w * __uint_as_float(a.z << 16);
        acc[5] += w * __uint_as_float(a.z & 0xFFFF0000u);
        acc[6] += w * __uint_as_float(a.w << 16);
        acc[7] += w * __uint_as_float(a.w & 0xFFFF0000u);
    };
    corner(z0, y0, x0, wz0 * wy0 * wx0);
    corner(z0, y0, x1, wz0 * wy0 * fx);
    corner(z0, y1, x0, wz0 * fy * wx0);
    corner(z0, y1, x1, wz0 * fy * fx);
    corner(z1, y0, x0, fz * wy0 * wx0);
    corner(z1, y0, x1, fz * wy0 * fx);
    corner(z1, y1, x0, fz * fy * wx0);
    corner(z1, y1, x1, fz * fy * fx);

    float4* o4 = reinterpret_cast<float4*>(out + (size_t)i * 8);
    o4[0] = make_float4(acc[0], acc[1], acc[2], acc[3]);
    o4[1] = make_float4(acc[4], acc[5], acc[6], acc[7]);
}

extern "C" void kernel_launch(void* const* d_in, const int* in_sizes, int n_in,
                              void* d_out, int out_size, void* d_ws, size_t ws_size,
                              hipStream_t stream) {
    const float* xyz     = (const float*)d_in[0];
    const float* approx  = (const float*)d_in[1];
    const float* detail0 = (const float*)d_in[2];
    const float* detail1 = (const float*)d_in[3];
    const float* detail2 = (const float*)d_in[4];
    float* out = (float*)d_out;
    int N = in_sizes[0] / 3;

    char* ws = (char*)d_ws;
    float* vol1 = (float*)ws;                                    // 8*64^3  f32 =   8 MiB
    float* vol2 = (float*)(ws + (size_t)8 * 1024 * 1024);        // 8*128^3 f32 =  64 MiB
    unsigned short* vol3 = (unsigned short*)(ws + (size_t)72 * 1024 * 1024); // 256^3*8 bf16 = 256 MiB

    // Level 0: 32 -> 64 (LDS-staged)
    idwt_passB<32><<<(32 * 32 * 32) / 256, 512, 0, stream>>>(approx, detail0, vol1);
    // Level 1: 64 -> 128 (LDS-staged)
    idwt_passB<64><<<(64 * 64 * 64) / 256, 512, 0, stream>>>(vol1, detail1, vol2);
    // Level 2: 128 -> 256, channel-last bf16, XCD-swizzled tiles
    idwt_passC2<<<(128 * 128 * 128) / 256, 512, 0, stream>>>(vol2, detail2, vol3);
    // Trilinear sampling from bf16 channel-last volume
    sample_kernel<<<(N + 255) / 256, 256, 0, stream>>>(xyz, vol3, out, N);
}

// Round 7
// 263.875 us; speedup vs baseline: 1.1159x; 1.0662x over previous
//
#include <hip/hip_runtime.h>

static constexpr float HS3 = 0.35355339059327373f; // (1/sqrt(2))^3

// s[m], m = sz*4+sy*2+sx (subband bits); o[p], p = pz*4+py*2+px (parity bits)
__device__ __forceinline__ void ihaar8(const float s[8], float o[8]) {
    float ex[8];
#pragma unroll
    for (int m = 0; m < 8; m += 2) { ex[m] = s[m] + s[m + 1]; ex[m + 1] = s[m] - s[m + 1]; }
    float ey[8];
#pragma unroll
    for (int i = 0; i < 2; ++i)
#pragma unroll
        for (int px = 0; px < 2; ++px) {
            ey[i * 4 + 0 + px] = ex[i * 4 + 0 + px] + ex[i * 4 + 2 + px];
            ey[i * 4 + 2 + px] = ex[i * 4 + 0 + px] - ex[i * 4 + 2 + px];
        }
#pragma unroll
    for (int q = 0; q < 4; ++q) {
        o[q]     = (ey[q] + ey[4 + q]) * HS3;
        o[4 + q] = (ey[q] - ey[4 + q]) * HS3;
    }
}

__device__ __forceinline__ unsigned short f2bf(float f) {
    unsigned int u = __float_as_uint(f);
    unsigned int r = (u + 0x7FFFu + ((u >> 16) & 1u)) >> 16; // RNE
    return (unsigned short)r;
}
__device__ __forceinline__ float bf2f(unsigned short u) {
    return __uint_as_float((unsigned int)u << 16);
}

// Fully fused 3-level inverse Haar: approx[8][32^3] + det0[7][8][32^3] + det1[7][8][64^3]
// + det2[7][8][128^3] (all f32) -> vol3 channel-last bf16 [256][256][256][8].
// Block = 512 threads = 256 L2-cells (2 output y-rows at fixed Z of the 128^3 cell grid).
// Haar cells are independent -> block needs exactly 1 det1 row, 1 det0/approx row, no halo.
__global__ __launch_bounds__(512) void idwt_fused(const float* __restrict__ approx,
                                                  const float* __restrict__ det0,
                                                  const float* __restrict__ det1,
                                                  const float* __restrict__ det2,
                                                  unsigned short* __restrict__ out) {
    __shared__ __align__(16) unsigned short ld2[56 * 256]; // det2 tile (bf16)    28 KiB
    __shared__ __align__(16) float ld1[56 * 64];           // det1 row            14 KiB
    __shared__ __align__(16) float ld0[64 * 32];           // approx+det0 row      8 KiB
    __shared__ __align__(16) float v1[8 * 64];             // vol1 row             2 KiB
    __shared__ __align__(16) float v2[16 * 128];           // vol2 rows [c*2+py][x] 8 KiB

    const int R3_2 = 128 * 128 * 128;
    const int R3_1 = 64 * 64 * 64;
    const int R3_0 = 32 * 32 * 32;

    int blk = blockIdx.x;          // 8192 blocks
    int Z = blk >> 6;              // 0..127 (L2 cell z)
    int k = blk & 63;              // y-pair: cells cover Y in {2k, 2k+1}
    int T0 = Z * 16384 + k * 256;  // base cell id in 128^3 linear
    int t = threadIdx.x;
    int wave = t >> 6, lane = t & 63;

    // ---- stage det2: waves 0-6, 8 streams each, 1 KiB contiguous per wave-load; f32->bf16
    if (wave < 7) {
        uint2* ld2u2 = reinterpret_cast<uint2*>(ld2); // [56][64] uint2
#pragma unroll
        for (int q = 0; q < 8; ++q) {
            int s = wave * 8 + q;
            float4 v = reinterpret_cast<const float4*>(det2 + (size_t)s * R3_2 + T0)[lane];
            uint2 pkd;
            pkd.x = (unsigned int)f2bf(v.x) | ((unsigned int)f2bf(v.y) << 16);
            pkd.y = (unsigned int)f2bf(v.z) | ((unsigned int)f2bf(v.w) << 16);
            ld2u2[s * 64 + lane] = pkd;
        }
    }
    // ---- stage det1 row (cz = Z>>1, cy = k): 56 streams x 64 floats = 896 float4
    {
        int cz = Z >> 1, cy = k;
        size_t rowoff = (size_t)cz * 4096 + (size_t)cy * 64;
        float4* d = reinterpret_cast<float4*>(ld1);
        {
            int s = t >> 4, f = t & 15;
            d[t] = reinterpret_cast<const float4*>(det1 + (size_t)s * R3_1 + rowoff)[f];
        }
        if (t < 384) {
            int idx = t + 512;
            int s = idx >> 4, f = idx & 15;
            d[idx] = reinterpret_cast<const float4*>(det1 + (size_t)s * R3_1 + rowoff)[f];
        }
    }
    // ---- stage approx+det0 row (z0 = Z>>2, y0 = k>>1): 64 streams x 32 floats = 512 float4
    {
        int z0 = Z >> 2, y0 = k >> 1;
        int s = t >> 3, f = t & 7;
        const float* base = (s < 8) ? (approx + (size_t)s * R3_0) : (det0 + (size_t)(s - 8) * R3_0);
        reinterpret_cast<float4*>(ld0)[t] = reinterpret_cast<const float4*>(base + z0 * 1024 + y0 * 32)[f];
    }
    __syncthreads();

    // ---- L0: 8ch x 32 cells, one ihaar8/thread (threads 0..255); keep parity (pz0,py0), both px
    if (t < 256) {
        int c = t >> 5, x0 = t & 31;
        float s8[8];
        s8[0] = ld0[c * 32 + x0];
#pragma unroll
        for (int bb = 0; bb < 7; ++bb) s8[bb + 1] = ld0[(8 + bb * 8 + c) * 32 + x0];
        float o[8];
        ihaar8(s8, o);
        int pz0 = (Z >> 1) & 1, py0 = k & 1;
        v1[c * 64 + 2 * x0 + 0] = o[pz0 * 4 + py0 * 2 + 0];
        v1[c * 64 + 2 * x0 + 1] = o[pz0 * 4 + py0 * 2 + 1];
    }
    __syncthreads();

    // ---- L1: 8ch x 64 cells, one ihaar8/thread; keep pz1 = Z&1, both py, both px
    {
        int c = t >> 6, x1 = t & 63;
        float s8[8];
        s8[0] = v1[c * 64 + x1];
#pragma unroll
        for (int bb = 0; bb < 7; ++bb) s8[bb + 1] = ld1[(bb * 8 + c) * 64 + x1];
        float o[8];
        ihaar8(s8, o);
        int pz1 = Z & 1;
#pragma unroll
        for (int py = 0; py < 2; ++py)
#pragma unroll
            for (int px = 0; px < 2; ++px)
                v2[(c * 2 + py) * 128 + 2 * x1 + px] = o[pz1 * 4 + py * 2 + px];
    }
    __syncthreads();

    // ---- L2 + bf16 channel-last store (cell = t>>1, h = t&1 -> contiguous 512B wave stores)
    int cell = t >> 1, h = t & 1;
    int cid = T0 + cell;
    int Y = (cid >> 7) & 127, X = cid & 127;
    int yb = cell >> 7;

    float ob[8][4]; // [parity][cc]
#pragma unroll
    for (int cc = 0; cc < 4; ++cc) {
        int c = h * 4 + cc;
        float s8[8];
        s8[0] = v2[(c * 2 + yb) * 128 + X];
#pragma unroll
        for (int bb = 0; bb < 7; ++bb) s8[bb + 1] = bf2f(ld2[(bb * 8 + c) * 256 + cell]);
        float o[8];
        ihaar8(s8, o);
#pragma unroll
        for (int p = 0; p < 8; ++p) ob[p][cc] = o[p];
    }

    uint2* out2 = reinterpret_cast<uint2*>(out);
#pragma unroll
    for (int pz = 0; pz < 2; ++pz)
#pragma unroll
        for (int py = 0; py < 2; ++py)
#pragma unroll
            for (int px = 0; px < 2; ++px) {
                int p = pz * 4 + py * 2 + px;
                size_t vox = (((size_t)(2 * Z + pz) * 256 + (2 * Y + py)) * 256 + (2 * X + px));
                uint2 v;
                v.x = (unsigned int)f2bf(ob[p][0]) | ((unsigned int)f2bf(ob[p][1]) << 16);
                v.y = (unsigned int)f2bf(ob[p][2]) | ((unsigned int)f2bf(ob[p][3]) << 16);
                out2[vox * 2 + h] = v;
            }
}

__device__ __forceinline__ float map_grid(float v) {
    float g = (v * (1.0f / 1.5f) + 1.0f) * (0.5f * 255.0f);
    return fminf(fmaxf(g, 0.0f), 255.0f);
}

__global__ void sample_kernel(const float* __restrict__ xyz, const unsigned short* __restrict__ vol,
                              float* __restrict__ out, int N) {
    int i = blockIdx.x * blockDim.x + threadIdx.x;
    if (i >= N) return;
    float gx = map_grid(xyz[3 * i + 0]);
    float gy = map_grid(xyz[3 * i + 1]);
    float gz = map_grid(xyz[3 * i + 2]);
    float x0f = floorf(gx), y0f = floorf(gy), z0f = floorf(gz);
    int x0 = (int)x0f, y0 = (int)y0f, z0 = (int)z0f;
    float fx = gx - x0f, fy = gy - y0f, fz = gz - z0f;
    int x1 = min(x0 + 1, 255), y1 = min(y0 + 1, 255), z1 = min(z0 + 1, 255);
    float wx0 = 1.0f - fx, wy0 = 1.0f - fy, wz0 = 1.0f - fz;

    float acc[8];
#pragma unroll
    for (int kk = 0; kk < 8; ++kk) acc[kk] = 0.0f;

    auto corner = [&](int z, int y, int x, float w) {
        const uint4* v4 = reinterpret_cast<const uint4*>(vol + ((((size_t)z * 256 + y) * 256 + x) << 3));
        uint4 a = *v4; // 8 bf16
        acc[0] += w * __uint_as_float(a.x << 16);
        acc[1] += w * __uint_as_float(a.x & 0xFFFF0000u);
        acc[2] += w * __uint_as_float(a.y << 16);
        acc[3] += w * __uint_as_float(a.y & 0xFFFF0000u);
        acc[4] += w * __uint_as_float(a.z << 16);
        acc[5] += w * __uint_as_float(a.z & 0xFFFF0000u);
        acc[6] += w * __uint_as_float(a.w << 16);
        acc[7] += w * __uint_as_float(a.w & 0xFFFF0000u);
    };
    corner(z0, y0, x0, wz0 * wy0 * wx0);
    corner(z0, y0, x1, wz0 * wy0 * fx);
    corner(z0, y1, x0, wz0 * fy * wx0);
    corner(z0, y1, x1, wz0 * fy * fx);
    corner(z1, y0, x0, fz * wy0 * wx0);
    corner(z1, y0, x1, fz * wy0 * fx);
    corner(z1, y1, x0, fz * fy * wx0);
    corner(z1, y1, x1, fz * fy * fx);

    float4* o4 = reinterpret_cast<float4*>(out + (size_t)i * 8);
    o4[0] = make_float4(acc[0], acc[1], acc[2], acc[3]);
    o4[1] = make_float4(acc[4], acc[5], acc[6], acc[7]);
}

extern "C" void kernel_launch(void* const* d_in, const int* in_sizes, int n_in,
                              void* d_out, int out_size, void* d_ws, size_t ws_size,
                              hipStream_t stream) {
    const float* xyz     = (const float*)d_in[0];
    const float* approx  = (const float*)d_in[1];
    const float* detail0 = (const float*)d_in[2];
    const float* detail1 = (const float*)d_in[3];
    const float* detail2 = (const float*)d_in[4];
    float* out = (float*)d_out;
    int N = in_sizes[0] / 3;

    unsigned short* vol3 = (unsigned short*)d_ws; // 256^3 * 8 bf16 = 256 MiB

    // Fused 3-level inverse wavelet -> channel-last bf16 volume
    idwt_fused<<<8192, 512, 0, stream>>>(approx, detail0, detail1, detail2, vol3);
    // Trilinear sampling
    sample_kernel<<<(N + 255) / 256, 256, 0, stream>>>(xyz, vol3, out, N);
}

// Round 9
// 247.355 us; speedup vs baseline: 1.1904x; 1.0668x over previous
//
#include <hip/hip_runtime.h>

static constexpr float HS3 = 0.35355339059327373f; // (1/sqrt(2))^3

typedef float nfloat4 __attribute__((ext_vector_type(4))); // native vec for NT builtins

// s[m], m = sz*4+sy*2+sx (subband bits); o[p], p = pz*4+py*2+px (parity bits)
__device__ __forceinline__ void ihaar8(const float s[8], float o[8]) {
    float ex[8];
#pragma unroll
    for (int m = 0; m < 8; m += 2) { ex[m] = s[m] + s[m + 1]; ex[m + 1] = s[m] - s[m + 1]; }
    float ey[8];
#pragma unroll
    for (int i = 0; i < 2; ++i)
#pragma unroll
        for (int px = 0; px < 2; ++px) {
            ey[i * 4 + 0 + px] = ex[i * 4 + 0 + px] + ex[i * 4 + 2 + px];
            ey[i * 4 + 2 + px] = ex[i * 4 + 0 + px] - ex[i * 4 + 2 + px];
        }
#pragma unroll
    for (int q = 0; q < 4; ++q) {
        o[q]     = (ey[q] + ey[4 + q]) * HS3;
        o[4 + q] = (ey[q] - ey[4 + q]) * HS3;
    }
}

__device__ __forceinline__ unsigned short f2bf(float f) {
    unsigned int u = __float_as_uint(f);
    unsigned int r = (u + 0x7FFFu + ((u >> 16) & 1u)) >> 16; // RNE
    return (unsigned short)r;
}
__device__ __forceinline__ float bf2f(unsigned short u) {
    return __uint_as_float((unsigned int)u << 16);
}

// Fully fused 3-level inverse Haar -> vol3 channel-last bf16 [256][256][256][8].
// det2 is read exactly once globally -> non-temporal loads keep it from evicting
// vol3 (256 MiB, exactly L3-sized) out of the Infinity Cache before the sampler.
__global__ __launch_bounds__(512) void idwt_fused(const float* __restrict__ approx,
                                                  const float* __restrict__ det0,
                                                  const float* __restrict__ det1,
                                                  const float* __restrict__ det2,
                                                  unsigned short* __restrict__ out) {
    __shared__ __align__(16) unsigned short ld2[56 * 256]; // det2 tile (bf16)    28 KiB
    __shared__ __align__(16) float ld1[56 * 64];           // det1 row            14 KiB
    __shared__ __align__(16) float ld0[64 * 32];           // approx+det0 row      8 KiB
    __shared__ __align__(16) float v1[8 * 64];             // vol1 row             2 KiB
    __shared__ __align__(16) float v2[16 * 128];           // vol2 rows            8 KiB

    const int R3_2 = 128 * 128 * 128;
    const int R3_1 = 64 * 64 * 64;
    const int R3_0 = 32 * 32 * 32;

    int blk = blockIdx.x;          // 8192 blocks
    int Z = blk >> 6;              // 0..127 (L2 cell z)
    int k = blk & 63;              // y-pair: cells cover Y in {2k, 2k+1}
    int T0 = Z * 16384 + k * 256;  // base cell id in 128^3 linear
    int t = threadIdx.x;
    int wave = t >> 6, lane = t & 63;

    // ---- stage det2 (non-temporal): waves 0-6, 8 streams each; f32->bf16
    if (wave < 7) {
        uint2* ld2u2 = reinterpret_cast<uint2*>(ld2); // [56][64] uint2
#pragma unroll
        for (int q = 0; q < 8; ++q) {
            int s = wave * 8 + q;
            nfloat4 v = __builtin_nontemporal_load(
                reinterpret_cast<const nfloat4*>(det2 + (size_t)s * R3_2 + T0) + lane);
            uint2 pkd;
            pkd.x = (unsigned int)f2bf(v.x) | ((unsigned int)f2bf(v.y) << 16);
            pkd.y = (unsigned int)f2bf(v.z) | ((unsigned int)f2bf(v.w) << 16);
            ld2u2[s * 64 + lane] = pkd;
        }
    }
    // ---- stage det1 row (cz = Z>>1, cy = k): 56 streams x 64 floats = 896 float4
    {
        int cz = Z >> 1, cy = k;
        size_t rowoff = (size_t)cz * 4096 + (size_t)cy * 64;
        float4* d = reinterpret_cast<float4*>(ld1);
        {
            int s = t >> 4, f = t & 15;
            d[t] = reinterpret_cast<const float4*>(det1 + (size_t)s * R3_1 + rowoff)[f];
        }
        if (t < 384) {
            int idx = t + 512;
            int s = idx >> 4, f = idx & 15;
            d[idx] = reinterpret_cast<const float4*>(det1 + (size_t)s * R3_1 + rowoff)[f];
        }
    }
    // ---- stage approx+det0 row (z0 = Z>>2, y0 = k>>1): 64 streams x 32 floats
    {
        int z0 = Z >> 2, y0 = k >> 1;
        int s = t >> 3, f = t & 7;
        const float* base = (s < 8) ? (approx + (size_t)s * R3_0) : (det0 + (size_t)(s - 8) * R3_0);
        reinterpret_cast<float4*>(ld0)[t] = reinterpret_cast<const float4*>(base + z0 * 1024 + y0 * 32)[f];
    }
    __syncthreads();

    // ---- L0: 8ch x 32 cells; keep parity (pz0,py0), both px
    if (t < 256) {
        int c = t >> 5, x0 = t & 31;
        float s8[8];
        s8[0] = ld0[c * 32 + x0];
#pragma unroll
        for (int bb = 0; bb < 7; ++bb) s8[bb + 1] = ld0[(8 + bb * 8 + c) * 32 + x0];
        float o[8];
        ihaar8(s8, o);
        int pz0 = (Z >> 1) & 1, py0 = k & 1;
        v1[c * 64 + 2 * x0 + 0] = o[pz0 * 4 + py0 * 2 + 0];
        v1[c * 64 + 2 * x0 + 1] = o[pz0 * 4 + py0 * 2 + 1];
    }
    __syncthreads();

    // ---- L1: 8ch x 64 cells; keep pz1 = Z&1, both py, both px
    {
        int c = t >> 6, x1 = t & 63;
        float s8[8];
        s8[0] = v1[c * 64 + x1];
#pragma unroll
        for (int bb = 0; bb < 7; ++bb) s8[bb + 1] = ld1[(bb * 8 + c) * 64 + x1];
        float o[8];
        ihaar8(s8, o);
        int pz1 = Z & 1;
#pragma unroll
        for (int py = 0; py < 2; ++py)
#pragma unroll
            for (int px = 0; px < 2; ++px)
                v2[(c * 2 + py) * 128 + 2 * x1 + px] = o[pz1 * 4 + py * 2 + px];
    }
    __syncthreads();

    // ---- L2 + bf16 channel-last store (cell = t>>1, h = t&1 -> contiguous 512B wave stores)
    int cell = t >> 1, h = t & 1;
    int cid = T0 + cell;
    int Y = (cid >> 7) & 127, X = cid & 127;
    int yb = cell >> 7;

    float ob[8][4]; // [parity][cc]
#pragma unroll
    for (int cc = 0; cc < 4; ++cc) {
        int c = h * 4 + cc;
        float s8[8];
        s8[0] = v2[(c * 2 + yb) * 128 + X];
#pragma unroll
        for (int bb = 0; bb < 7; ++bb) s8[bb + 1] = bf2f(ld2[(bb * 8 + c) * 256 + cell]);
        float o[8];
        ihaar8(s8, o);
#pragma unroll
        for (int p = 0; p < 8; ++p) ob[p][cc] = o[p];
    }

    uint2* out2 = reinterpret_cast<uint2*>(out);
#pragma unroll
    for (int pz = 0; pz < 2; ++pz)
#pragma unroll
        for (int py = 0; py < 2; ++py)
#pragma unroll
            for (int px = 0; px < 2; ++px) {
                int p = pz * 4 + py * 2 + px;
                size_t vox = (((size_t)(2 * Z + pz) * 256 + (2 * Y + py)) * 256 + (2 * X + px));
                uint2 v;
                v.x = (unsigned int)f2bf(ob[p][0]) | ((unsigned int)f2bf(ob[p][1]) << 16);
                v.y = (unsigned int)f2bf(ob[p][2]) | ((unsigned int)f2bf(ob[p][3]) << 16);
                out2[vox * 2 + h] = v;
            }
}

__device__ __forceinline__ float map_grid(float v) {
    float g = (v * (1.0f / 1.5f) + 1.0f) * (0.5f * 255.0f);
    return fminf(fmaxf(g, 0.0f), 255.0f);
}

__global__ void sample_kernel(const float* __restrict__ xyz, const unsigned short* __restrict__ vol,
                              float* __restrict__ out, int N) {
    int i = blockIdx.x * blockDim.x + threadIdx.x;
    if (i >= N) return;
    float gx = map_grid(__builtin_nontemporal_load(xyz + 3 * i + 0));
    float gy = map_grid(__builtin_nontemporal_load(xyz + 3 * i + 1));
    float gz = map_grid(__builtin_nontemporal_load(xyz + 3 * i + 2));
    float x0f = floorf(gx), y0f = floorf(gy), z0f = floorf(gz);
    int x0 = (int)x0f, y0 = (int)y0f, z0 = (int)z0f;
    float fx = gx - x0f, fy = gy - y0f, fz = gz - z0f;
    int x1 = min(x0 + 1, 255), y1 = min(y0 + 1, 255), z1 = min(z0 + 1, 255);
    float wx0 = 1.0f - fx, wy0 = 1.0f - fy, wz0 = 1.0f - fz;

    float acc[8];
#pragma unroll
    for (int kk = 0; kk < 8; ++kk) acc[kk] = 0.0f;

    auto corner = [&](int z, int y, int x, float w) {
        const uint4* v4 = reinterpret_cast<const uint4*>(vol + ((((size_t)z * 256 + y) * 256 + x) << 3));
        uint4 a = *v4; // 8 bf16
        acc[0] += w * __uint_as_float(a.x << 16);
        acc[1] += w * __uint_as_float(a.x & 0xFFFF0000u);
        acc[2] += w * __uint_as_float(a.y << 16);
        acc[3] += w * __uint_as_float(a.y & 0xFFFF0000u);
        acc[4] += w * __uint_as_float(a.z << 16);
        acc[5] += w * __uint_as_float(a.z & 0xFFFF0000u);
        acc[6] += w * __uint_as_float(a.w << 16);
        acc[7] += w * __uint_as_float(a.w & 0xFFFF0000u);
    };
    corner(z0, y0, x0, wz0 * wy0 * wx0);
    corner(z0, y0, x1, wz0 * wy0 * fx);
    corner(z0, y1, x0, wz0 * fy * wx0);
    corner(z0, y1, x1, wz0 * fy * fx);
    corner(z1, y0, x0, fz * wy0 * wx0);
    corner(z1, y0, x1, fz * wy0 * fx);
    corner(z1, y1, x0, fz * fy * wx0);
    corner(z1, y1, x1, fz * fy * fx);

    nfloat4 o0 = {acc[0], acc[1], acc[2], acc[3]};
    nfloat4 o1 = {acc[4], acc[5], acc[6], acc[7]};
    nfloat4* o4 = reinterpret_cast<nfloat4*>(out + (size_t)i * 8);
    __builtin_nontemporal_store(o0, o4);
    __builtin_nontemporal_store(o1, o4 + 1);
}

extern "C" void kernel_launch(void* const* d_in, const int* in_sizes, int n_in,
                              void* d_out, int out_size, void* d_ws, size_t ws_size,
                              hipStream_t stream) {
    const float* xyz     = (const float*)d_in[0];
    const float* approx  = (const float*)d_in[1];
    const float* detail0 = (const float*)d_in[2];
    const float* detail1 = (const float*)d_in[3];
    const float* detail2 = (const float*)d_in[4];
    float* out = (float*)d_out;
    int N = in_sizes[0] / 3;

    unsigned short* vol3 = (unsigned short*)d_ws; // 256^3 * 8 bf16 = 256 MiB

    // Fused 3-level inverse wavelet -> channel-last bf16 volume
    idwt_fused<<<8192, 512, 0, stream>>>(approx, detail0, detail1, detail2, vol3);
    // Trilinear sampling
    sample_kernel<<<(N + 255) / 256, 256, 0, stream>>>(xyz, vol3, out, N);
}

// Round 10
// 241.539 us; speedup vs baseline: 1.2191x; 1.0241x over previous
//
#include <hip/hip_runtime.h>

static constexpr float HS3 = 0.35355339059327373f; // (1/sqrt(2))^3

typedef float nfloat4 __attribute__((ext_vector_type(4))); // native vec for NT builtins

// s[m], m = sz*4+sy*2+sx (subband bits); o[p], p = pz*4+py*2+px (parity bits)
__device__ __forceinline__ void ihaar8(const float s[8], float o[8]) {
    float ex[8];
#pragma unroll
    for (int m = 0; m < 8; m += 2) { ex[m] = s[m] + s[m + 1]; ex[m + 1] = s[m] - s[m + 1]; }
    float ey[8];
#pragma unroll
    for (int i = 0; i < 2; ++i)
#pragma unroll
        for (int px = 0; px < 2; ++px) {
            ey[i * 4 + 0 + px] = ex[i * 4 + 0 + px] + ex[i * 4 + 2 + px];
            ey[i * 4 + 2 + px] = ex[i * 4 + 0 + px] - ex[i * 4 + 2 + px];
        }
#pragma unroll
    for (int q = 0; q < 4; ++q) {
        o[q]     = (ey[q] + ey[4 + q]) * HS3;
        o[4 + q] = (ey[q] - ey[4 + q]) * HS3;
    }
}

__device__ __forceinline__ unsigned short f2bf(float f) {
    unsigned int u = __float_as_uint(f);
    unsigned int r = (u + 0x7FFFu + ((u >> 16) & 1u)) >> 16; // RNE
    return (unsigned short)r;
}
__device__ __forceinline__ float bf2f(unsigned short u) {
    return __uint_as_float((unsigned int)u << 16);
}

// Fully fused 3-level inverse Haar -> vol3 channel-last bf16 [256][256][256][8].
// det2 non-temporal (single-use; keeps vol3 L3-resident for the sampler).
// LDS: ld0 and v2 are time-disjoint (barrier between last ld0 read and first v2
// write) -> aliased in one 8 KiB buffer. Total 52 KiB -> 3 blocks/CU.
__global__ __launch_bounds__(512) void idwt_fused(const float* __restrict__ approx,
                                                  const float* __restrict__ det0,
                                                  const float* __restrict__ det1,
                                                  const float* __restrict__ det2,
                                                  unsigned short* __restrict__ out) {
    __shared__ __align__(16) unsigned short ld2[56 * 256]; // det2 tile (bf16)    28 KiB
    __shared__ __align__(16) float ld1[56 * 64];           // det1 row            14 KiB
    __shared__ __align__(16) float ld0v2[16 * 128];        // ld0 (64x32) / v2 (16x128) 8 KiB
    __shared__ __align__(16) float v1[8 * 64];             // vol1 row             2 KiB

    float* const ld0 = ld0v2; // [64][32] view, dead after L0 phase
    float* const v2  = ld0v2; // [16][128] view, live from L1 phase

    const int R3_2 = 128 * 128 * 128;
    const int R3_1 = 64 * 64 * 64;
    const int R3_0 = 32 * 32 * 32;

    int blk = blockIdx.x;          // 8192 blocks
    int Z = blk >> 6;              // 0..127 (L2 cell z)
    int k = blk & 63;              // y-pair: cells cover Y in {2k, 2k+1}
    int T0 = Z * 16384 + k * 256;  // base cell id in 128^3 linear
    int t = threadIdx.x;
    int wave = t >> 6, lane = t & 63;

    // ---- stage det2 (non-temporal): waves 0-6, 8 streams each; f32->bf16
    if (wave < 7) {
        uint2* ld2u2 = reinterpret_cast<uint2*>(ld2); // [56][64] uint2
#pragma unroll
        for (int q = 0; q < 8; ++q) {
            int s = wave * 8 + q;
            nfloat4 v = __builtin_nontemporal_load(
                reinterpret_cast<const nfloat4*>(det2 + (size_t)s * R3_2 + T0) + lane);
            uint2 pkd;
            pkd.x = (unsigned int)f2bf(v.x) | ((unsigned int)f2bf(v.y) << 16);
            pkd.y = (unsigned int)f2bf(v.z) | ((unsigned int)f2bf(v.w) << 16);
            ld2u2[s * 64 + lane] = pkd;
        }
    }
    // ---- stage det1 row (cz = Z>>1, cy = k): 56 streams x 64 floats = 896 float4
    {
        int cz = Z >> 1, cy = k;
        size_t rowoff = (size_t)cz * 4096 + (size_t)cy * 64;
        float4* d = reinterpret_cast<float4*>(ld1);
        {
            int s = t >> 4, f = t & 15;
            d[t] = reinterpret_cast<const float4*>(det1 + (size_t)s * R3_1 + rowoff)[f];
        }
        if (t < 384) {
            int idx = t + 512;
            int s = idx >> 4, f = idx & 15;
            d[idx] = reinterpret_cast<const float4*>(det1 + (size_t)s * R3_1 + rowoff)[f];
        }
    }
    // ---- stage approx+det0 row (z0 = Z>>2, y0 = k>>1): 64 streams x 32 floats
    {
        int z0 = Z >> 2, y0 = k >> 1;
        int s = t >> 3, f = t & 7;
        const float* base = (s < 8) ? (approx + (size_t)s * R3_0) : (det0 + (size_t)(s - 8) * R3_0);
        reinterpret_cast<float4*>(ld0)[t] = reinterpret_cast<const float4*>(base + z0 * 1024 + y0 * 32)[f];
    }
    __syncthreads();

    // ---- L0: 8ch x 32 cells; keep parity (pz0,py0), both px
    if (t < 256) {
        int c = t >> 5, x0 = t & 31;
        float s8[8];
        s8[0] = ld0[c * 32 + x0];
#pragma unroll
        for (int bb = 0; bb < 7; ++bb) s8[bb + 1] = ld0[(8 + bb * 8 + c) * 32 + x0];
        float o[8];
        ihaar8(s8, o);
        int pz0 = (Z >> 1) & 1, py0 = k & 1;
        v1[c * 64 + 2 * x0 + 0] = o[pz0 * 4 + py0 * 2 + 0];
        v1[c * 64 + 2 * x0 + 1] = o[pz0 * 4 + py0 * 2 + 1];
    }
    __syncthreads(); // after this barrier ld0 is dead; v2 may overwrite it

    // ---- L1: 8ch x 64 cells; keep pz1 = Z&1, both py, both px
    {
        int c = t >> 6, x1 = t & 63;
        float s8[8];
        s8[0] = v1[c * 64 + x1];
#pragma unroll
        for (int bb = 0; bb < 7; ++bb) s8[bb + 1] = ld1[(bb * 8 + c) * 64 + x1];
        float o[8];
        ihaar8(s8, o);
        int pz1 = Z & 1;
#pragma unroll
        for (int py = 0; py < 2; ++py)
#pragma unroll
            for (int px = 0; px < 2; ++px)
                v2[(c * 2 + py) * 128 + 2 * x1 + px] = o[pz1 * 4 + py * 2 + px];
    }
    __syncthreads();

    // ---- L2 + bf16 channel-last store (cell = t>>1, h = t&1 -> contiguous 512B wave stores)
    int cell = t >> 1, h = t & 1;
    int cid = T0 + cell;
    int Y = (cid >> 7) & 127, X = cid & 127;
    int yb = cell >> 7;

    float ob[8][4]; // [parity][cc]
#pragma unroll
    for (int cc = 0; cc < 4; ++cc) {
        int c = h * 4 + cc;
        float s8[8];
        s8[0] = v2[(c * 2 + yb) * 128 + X];
#pragma unroll
        for (int bb = 0; bb < 7; ++bb) s8[bb + 1] = bf2f(ld2[(bb * 8 + c) * 256 + cell]);
        float o[8];
        ihaar8(s8, o);
#pragma unroll
        for (int p = 0; p < 8; ++p) ob[p][cc] = o[p];
    }

    uint2* out2 = reinterpret_cast<uint2*>(out);
#pragma unroll
    for (int pz = 0; pz < 2; ++pz)
#pragma unroll
        for (int py = 0; py < 2; ++py)
#pragma unroll
            for (int px = 0; px < 2; ++px) {
                int p = pz * 4 + py * 2 + px;
                size_t vox = (((size_t)(2 * Z + pz) * 256 + (2 * Y + py)) * 256 + (2 * X + px));
                uint2 v;
                v.x = (unsigned int)f2bf(ob[p][0]) | ((unsigned int)f2bf(ob[p][1]) << 16);
                v.y = (unsigned int)f2bf(ob[p][2]) | ((unsigned int)f2bf(ob[p][3]) << 16);
                out2[vox * 2 + h] = v;
            }
}

__device__ __forceinline__ float map_grid(float v) {
    float g = (v * (1.0f / 1.5f) + 1.0f) * (0.5f * 255.0f);
    return fminf(fmaxf(g, 0.0f), 255.0f);
}

__global__ void sample_kernel(const float* __restrict__ xyz, const unsigned short* __restrict__ vol,
                              float* __restrict__ out, int N) {
    int i = blockIdx.x * blockDim.x + threadIdx.x;
    if (i >= N) return;
    float gx = map_grid(__builtin_nontemporal_load(xyz + 3 * i + 0));
    float gy = map_grid(__builtin_nontemporal_load(xyz + 3 * i + 1));
    float gz = map_grid(__builtin_nontemporal_load(xyz + 3 * i + 2));
    float x0f = floorf(gx), y0f = floorf(gy), z0f = floorf(gz);
    int x0 = (int)x0f, y0 = (int)y0f, z0 = (int)z0f;
    float fx = gx - x0f, fy = gy - y0f, fz = gz - z0f;
    int x1 = min(x0 + 1, 255), y1 = min(y0 + 1, 255), z1 = min(z0 + 1, 255);
    float wx0 = 1.0f - fx, wy0 = 1.0f - fy, wz0 = 1.0f - fz;

    float acc[8];
#pragma unroll
    for (int kk = 0; kk < 8; ++kk) acc[kk] = 0.0f;

    auto corner = [&](int z, int y, int x, float w) {
        const uint4* v4 = reinterpret_cast<const uint4*>(vol + ((((size_t)z * 256 + y) * 256 + x) << 3));
        uint4 a = *v4; // 8 bf16
        acc[0] += w * __uint_as_float(a.x << 16);
        acc[1] += w * __uint_as_float(a.x & 0xFFFF0000u);
        acc[2] += w * __uint_as_float(a.y << 16);
        acc[3] += w * __uint_as_float(a.y & 0xFFFF0000u);
        acc[4] += w * __uint_as_float(a.z << 16);
        acc[5] += w * __uint_as_float(a.z & 0xFFFF0000u);
        acc[6] += w * __uint_as_float(a.w << 16);
        acc[7] += w * __uint_as_float(a.w & 0xFFFF0000u);
    };
    corner(z0, y0, x0, wz0 * wy0 * wx0);
    corner(z0, y0, x1, wz0 * wy0 * fx);
    corner(z0, y1, x0, wz0 * fy * wx0);
    corner(z0, y1, x1, wz0 * fy * fx);
    corner(z1, y0, x0, fz * wy0 * wx0);
    corner(z1, y0, x1, fz * wy0 * fx);
    corner(z1, y1, x0, fz * fy * wx0);
    corner(z1, y1, x1, fz * fy * fx);

    nfloat4 o0 = {acc[0], acc[1], acc[2], acc[3]};
    nfloat4 o1 = {acc[4], acc[5], acc[6], acc[7]};
    nfloat4* o4 = reinterpret_cast<nfloat4*>(out + (size_t)i * 8);
    __builtin_nontemporal_store(o0, o4);
    __builtin_nontemporal_store(o1, o4 + 1);
}

extern "C" void kernel_launch(void* const* d_in, const int* in_sizes, int n_in,
                              void* d_out, int out_size, void* d_ws, size_t ws_size,
                              hipStream_t stream) {
    const float* xyz     = (const float*)d_in[0];
    const float* approx  = (const float*)d_in[1];
    const float* detail0 = (const float*)d_in[2];
    const float* detail1 = (const float*)d_in[3];
    const float* detail2 = (const float*)d_in[4];
    float* out = (float*)d_out;
    int N = in_sizes[0] / 3;

    unsigned short* vol3 = (unsigned short*)d_ws; // 256^3 * 8 bf16 = 256 MiB

    // Fused 3-level inverse wavelet -> channel-last bf16 volume
    idwt_fused<<<8192, 512, 0, stream>>>(approx, detail0, detail1, detail2, vol3);
    // Trilinear sampling
    sample_kernel<<<(N + 255) / 256, 256, 0, stream>>>(xyz, vol3, out, N);
}